// Round 3
// baseline (252.803 us; speedup 1.0000x reference)
//
#include <hip/hip_runtime.h>
#include <hip/hip_bf16.h>

typedef __hip_bfloat16 bf16;

#define P_CNT 16
#define J_CNT 23

// Device-global scratch (no dependence on d_ws).
__device__ int    g_flag;                    // 0 = fp32 in/out, 1 = bf16 in/out
__device__ float4 g_A[P_CNT * J_CNT * 3];    // per-(p,j) 3x4 skinning matrix rows
__device__ float  g_shift[P_CNT * 3];

struct PosePtrs { const void* p[11]; };

template <bool BF>
__device__ __forceinline__ float ld(const void* p, long long i) {
    if (BF) return __bfloat162float(((const bf16*)p)[i]);
    return ((const float*)p)[i];
}
template <bool BF>
__device__ __forceinline__ void st(void* p, long long i, float v) {
    if (BF) ((bf16*)p)[i] = __float2bfloat16(v);
    else    ((float*)p)[i] = v;
}

// Decide input dtype from the invariant sum(weights row r) == 1.0, rows 0..3.
// Requiring ALL 4 aligned row-sums near 1 makes false-accept ~1e-5.
__global__ void detect_kernel(const void* __restrict__ w) {
    if (threadIdx.x != 0 || blockIdx.x != 0) return;
    const float* wf = (const float*)w;
    const bf16*  wb = (const bf16*)w;
    bool ok_f = true, ok_b = true;
    for (int r = 0; r < 4; ++r) {
        float sf = 0.f, sb = 0.f;
        for (int j = 0; j < J_CNT; ++j) {
            sf += wf[r * J_CNT + j];
            sb += __bfloat162float(wb[r * J_CNT + j]);
        }
        if (!(fabsf(sf - 1.f) < 0.02f)) ok_f = false;   // NaN-safe
        if (!(fabsf(sb - 1.f) < 0.10f)) ok_b = false;
    }
    g_flag = (!ok_f && ok_b) ? 1 : 0;
}

// One thread per pose (16 active). Builds g_A, g_shift, and output-1.
template <bool BF>
__global__ void pose_kernel(const void* __restrict__ joints,
                            const void* __restrict__ disp,
                            const void* __restrict__ rdis,
                            PosePtrs pp,
                            void* __restrict__ out1)     // [P][J][3]
{
    if (g_flag != (BF ? 1 : 0)) return;
    __shared__ float Gs[P_CNT][J_CNT][12];   // global transforms, affine rows [R|t]
    int p = threadIdx.x;
    if (p >= P_CNT) return;

    const int par[J_CNT]     = {-1,0,1,1,3,4,5,4,7,4,9,1,11,12,13,12,15,12,17,0,19,0,21};
    const int slot_of[J_CNT] = {0,-1,-1,1,2,3,-1,4,-1,5,-1,6,7,8,-1,9,-1,10,-1,-1,-1,-1,-1};
    const float slot_sc[11]  = {
        0.7853981633974483f, 1.5707963267948966f, 1.5707963267948966f, 0.7853981633974483f,
        0.7853981633974483f, 0.7853981633974483f, 1.5707963267948966f, 1.5707963267948966f,
        0.7853981633974483f, 0.7853981633974483f, 0.7853981633974483f};

    for (int j = 0; j < J_CNT; ++j) {
        float rx = 0.f, ry = 0.f, rz = 0.f;
        int s = slot_of[j];
        if (s >= 0) {
            float sc = slot_sc[s];
            rx = sc * tanhf(ld<BF>(pp.p[s], p * 3 + 0));
            ry = sc * tanhf(ld<BF>(pp.p[s], p * 3 + 1));
            rz = sc * tanhf(ld<BF>(pp.p[s], p * 3 + 2));
        }
        float ang = sqrtf(rx * rx + ry * ry + rz * rz + 1e-16f);
        float sn = sinf(ang), cs = cosf(ang);
        float C = 1.f - cs;
        float inva = 1.f / ang;
        float x = rx * inva, y = ry * inva, z = rz * inva;
        float R[3][3];
        R[0][0] = 1.f - C * (y * y + z * z); R[0][1] = -sn * z + C * x * y;       R[0][2] = sn * y + C * x * z;
        R[1][0] = sn * z + C * x * y;        R[1][1] = 1.f - C * (x * x + z * z); R[1][2] = -sn * x + C * y * z;
        R[2][0] = -sn * y + C * x * z;       R[2][1] = sn * x + C * y * z;        R[2][2] = 1.f - C * (x * x + y * y);

        int q = par[j];
        float t[3];
        for (int c = 0; c < 3; ++c) {
            float jc = ld<BF>(joints, j * 3 + c);
            t[c] = (j == 0) ? jc : (jc - ld<BF>(joints, q * 3 + c));
        }
        if (j == 0) {
            for (int i = 0; i < 3; ++i) {
                Gs[p][0][i * 4 + 0] = R[i][0];
                Gs[p][0][i * 4 + 1] = R[i][1];
                Gs[p][0][i * 4 + 2] = R[i][2];
                Gs[p][0][i * 4 + 3] = t[i];
            }
        } else {
            for (int i = 0; i < 3; ++i) {
                float g0 = Gs[p][q][i * 4 + 0], g1 = Gs[p][q][i * 4 + 1];
                float g2 = Gs[p][q][i * 4 + 2], g3 = Gs[p][q][i * 4 + 3];
                Gs[p][j][i * 4 + 0] = g0 * R[0][0] + g1 * R[1][0] + g2 * R[2][0];
                Gs[p][j][i * 4 + 1] = g0 * R[0][1] + g1 * R[1][1] + g2 * R[2][1];
                Gs[p][j][i * 4 + 2] = g0 * R[0][2] + g1 * R[1][2] + g2 * R[2][2];
                Gs[p][j][i * 4 + 3] = g0 * t[0] + g1 * t[1] + g2 * t[2] + g3;
            }
        }
    }

    float sh[3];
    for (int c = 0; c < 3; ++c) {
        sh[c] = ld<BF>(rdis, p * 3 + c) + 3.f * tanhf(ld<BF>(disp, p * 3 + c));
        g_shift[p * 3 + c] = sh[c];
    }

    for (int j = 0; j < J_CNT; ++j) {
        float jx = ld<BF>(joints, j * 3 + 0);
        float jy = ld<BF>(joints, j * 3 + 1);
        float jz = ld<BF>(joints, j * 3 + 2);
        for (int i = 0; i < 3; ++i) {
            float g0 = Gs[p][j][i * 4 + 0], g1 = Gs[p][j][i * 4 + 1];
            float g2 = Gs[p][j][i * 4 + 2], g3 = Gs[p][j][i * 4 + 3];
            g_A[(p * J_CNT + j) * 3 + i] =
                make_float4(g0, g1, g2, g3 - (g0 * jx + g1 * jy + g2 * jz));
            st<BF>(out1, (p * J_CNT + j) * 3 + i, g3 + sh[i]);
        }
    }
}

// One thread per vertex, loops over all 16 poses.
template <bool BF>
__global__ __launch_bounds__(256) void lbs_vertex(
    const void* __restrict__ verts,     // [V][3]
    const void* __restrict__ weights,   // [V][23]
    void* __restrict__ out0,            // [P][V][3]
    int V)
{
    if (g_flag != (BF ? 1 : 0)) return;
    __shared__ float4 As[P_CNT * J_CNT * 3];   // 17.25 KB
    __shared__ float  sh[P_CNT * 3];
    for (int i = threadIdx.x; i < P_CNT * J_CNT * 3; i += 256) As[i] = g_A[i];
    for (int i = threadIdx.x; i < P_CNT * 3; i += 256) sh[i] = g_shift[i];
    __syncthreads();

    int v = blockIdx.x * 256 + threadIdx.x;
    if (v >= V) return;

    float w[J_CNT];
    long long wbase = (long long)v * J_CNT;
#pragma unroll
    for (int j = 0; j < J_CNT; ++j) w[j] = ld<BF>(weights, wbase + j);
    float x = ld<BF>(verts, (long long)v * 3 + 0);
    float y = ld<BF>(verts, (long long)v * 3 + 1);
    float z = ld<BF>(verts, (long long)v * 3 + 2);

    for (int p = 0; p < P_CNT; ++p) {
        const float4* Ap = As + p * (J_CNT * 3);
        float4 t0 = make_float4(0.f, 0.f, 0.f, 0.f);
        float4 t1 = make_float4(0.f, 0.f, 0.f, 0.f);
        float4 t2 = make_float4(0.f, 0.f, 0.f, 0.f);
#pragma unroll
        for (int j = 0; j < J_CNT; ++j) {
            float wj = w[j];
            float4 a0 = Ap[j * 3 + 0], a1 = Ap[j * 3 + 1], a2 = Ap[j * 3 + 2];
            t0.x = fmaf(wj, a0.x, t0.x); t0.y = fmaf(wj, a0.y, t0.y);
            t0.z = fmaf(wj, a0.z, t0.z); t0.w = fmaf(wj, a0.w, t0.w);
            t1.x = fmaf(wj, a1.x, t1.x); t1.y = fmaf(wj, a1.y, t1.y);
            t1.z = fmaf(wj, a1.z, t1.z); t1.w = fmaf(wj, a1.w, t1.w);
            t2.x = fmaf(wj, a2.x, t2.x); t2.y = fmaf(wj, a2.y, t2.y);
            t2.z = fmaf(wj, a2.z, t2.z); t2.w = fmaf(wj, a2.w, t2.w);
        }
        float ox = fmaf(t0.x, x, fmaf(t0.y, y, fmaf(t0.z, z, t0.w))) + sh[p * 3 + 0];
        float oy = fmaf(t1.x, x, fmaf(t1.y, y, fmaf(t1.z, z, t1.w))) + sh[p * 3 + 1];
        float oz = fmaf(t2.x, x, fmaf(t2.y, y, fmaf(t2.z, z, t2.w))) + sh[p * 3 + 2];
        long long base = ((long long)p * V + v) * 3;
        st<BF>(out0, base + 0, ox);
        st<BF>(out0, base + 1, oy);
        st<BF>(out0, base + 2, oz);
    }
}

extern "C" void kernel_launch(void* const* d_in, const int* in_sizes, int n_in,
                              void* d_out, int out_size, void* d_ws, size_t ws_size,
                              hipStream_t stream) {
    const void* verts   = d_in[0];  // (1,V,3)
    const void* joints  = d_in[1];  // (1,23,3)
    const void* weights = d_in[2];  // (V,23)
    const void* disp    = d_in[3];  // (16,1,3)
    const void* rdis    = d_in[4];  // (16,3)
    PosePtrs pp;
    for (int i = 0; i < 11; ++i) pp.p[i] = d_in[5 + i];

    int V = in_sizes[0] / 3;  // 500000
    long long pv3 = (long long)P_CNT * V * 3;

    // out1 immediately follows out0 in flat element order; element size per dtype
    void* out1_f = (void*)((float*)d_out + pv3);
    void* out1_b = (void*)((bf16*) d_out + pv3);

    detect_kernel<<<1, 64, 0, stream>>>(weights);
    pose_kernel<false><<<1, 64, 0, stream>>>(joints, disp, rdis, pp, out1_f);
    pose_kernel<true ><<<1, 64, 0, stream>>>(joints, disp, rdis, pp, out1_b);
    int G = (V + 255) / 256;
    lbs_vertex<false><<<G, 256, 0, stream>>>(verts, weights, d_out, V);
    lbs_vertex<true ><<<G, 256, 0, stream>>>(verts, weights, d_out, V);
}